// Round 1
// baseline (35269.354 us; speedup 1.0000x reference)
//
#include <hip/hip_runtime.h>
#include <hip/hip_bf16.h>
#include <math.h>

#define SIDE 48
#define PPOS (SIDE*SIDE)        // 2304 positions
#define NHYP 4
#define FD 32
#define K9 9
#define RD 8
#define JOINT 104               // 3*FD + RD
#define HID 64
#define NBP (2*PPOS)            // 4608 (B*P)
#define NOUT (NBP*NHYP)         // 18432 (B*P*H)
#define POS_PER_BLK 4
#define THREADS (POS_PER_BLK*144)  // 576 = 9 waves

__device__ __forceinline__ float softplusf(float v) {
    // jax.nn.softplus = logaddexp(v, 0) = max(v,0) + log1p(exp(-|v|))
    return fmaxf(v, 0.f) + log1pf(expf(-fabsf(v)));
}

__global__ __launch_bounds__(THREADS) void eml_main(
    const float* __restrict__ hs, const float* __restrict__ act_in,
    const float* __restrict__ drive, const float* __restrict__ resist,
    const float* __restrict__ rel, const float* __restrict__ ln_w,
    const float* __restrict__ ln_b,
    const float* __restrict__ sup_w1, const float* __restrict__ sup_b1,
    const float* __restrict__ sup_w2, const float* __restrict__ sup_b2,
    const float* __restrict__ con_w1, const float* __restrict__ con_b1,
    const float* __restrict__ con_w2, const float* __restrict__ con_b2,
    const float* __restrict__ eml_bias, float* __restrict__ out)
{
    __shared__ float sW[JOINT*128];       // cols 0..63 = sup_w1, 64..127 = con_w1
    __shared__ float sB1[128];
    __shared__ float sW2[128];
    __shared__ float slnw[JOINT], slnb[JOINT];
    __shared__ float svg[THREADS], cvg[THREADS];
    __shared__ float sgate[POS_PER_BLK*36];

    const int tid = threadIdx.x;

    for (int i = tid; i < JOINT*128; i += THREADS) {
        int k = i >> 7, j = i & 127;
        sW[i] = (j < HID) ? sup_w1[k*HID + j] : con_w1[k*HID + (j - HID)];
    }
    if (tid < 128) {
        sB1[tid] = (tid < HID) ? sup_b1[tid] : con_b1[tid - HID];
        sW2[tid] = (tid < HID) ? sup_w2[tid] : con_w2[tid - HID];
    }
    if (tid < JOINT) { slnw[tid] = ln_w[tid]; slnb[tid] = ln_b[tid]; }
    __syncthreads();

    // thread -> (pos within block, h, k, h2)
    const int pos = tid / 144;
    const int r   = tid % 144;
    const int h   = r / 36;
    const int s   = r % 36;
    const int k   = s >> 2;
    const int h2  = s & 3;

    const int bp = blockIdx.x * POS_PER_BLK + pos;
    const int b  = bp / PPOS;
    const int p  = bp % PPOS;
    const int y  = p / SIDE, x = p % SIDE;
    const int ny = y + (k/3) - 1, nx = x + (k%3) - 1;
    const bool vld = (ny >= 0) && (ny < SIDE) && (nx >= 0) && (nx < SIDE);
    const int nbp = b*PPOS + ny*SIDE + nx;   // only used when vld

    // ---- build joint vector ----
    float tgt[FD], src[FD];
    {
        const float4* t4 = reinterpret_cast<const float4*>(hs + (size_t)(bp*NHYP + h)*FD);
        #pragma unroll
        for (int i = 0; i < 8; ++i) {
            float4 v = t4[i];
            tgt[4*i+0]=v.x; tgt[4*i+1]=v.y; tgt[4*i+2]=v.z; tgt[4*i+3]=v.w;
        }
        if (vld) {
            const float4* s4 = reinterpret_cast<const float4*>(hs + (size_t)(nbp*NHYP + h2)*FD);
            #pragma unroll
            for (int i = 0; i < 8; ++i) {
                float4 v = s4[i];
                src[4*i+0]=v.x; src[4*i+1]=v.y; src[4*i+2]=v.z; src[4*i+3]=v.w;
            }
        } else {
            #pragma unroll
            for (int i = 0; i < FD; ++i) src[i] = 0.f;
        }
    }

    float jn[JOINT];
    #pragma unroll
    for (int i = 0; i < FD; ++i) {
        jn[i]       = tgt[i];
        jn[FD+i]    = src[i];
        jn[2*FD+i]  = tgt[i] - src[i];
    }
    #pragma unroll
    for (int i = 0; i < RD; ++i) jn[3*FD+i] = rel[k*RD + i];

    // ---- LayerNorm over 104 ----
    float sum = 0.f, ss = 0.f;
    #pragma unroll
    for (int i = 0; i < JOINT; ++i) { sum += jn[i]; ss += jn[i]*jn[i]; }
    const float mu   = sum * (1.0f/JOINT);
    const float var  = ss * (1.0f/JOINT) - mu*mu;
    const float rinv = rsqrtf(var + 1e-5f);
    #pragma unroll
    for (int i = 0; i < JOINT; ++i) jn[i] = (jn[i]-mu)*rinv*slnw[i] + slnb[i];

    // ---- two MLPs (combined 128 hidden cols) ----
    float outs = 0.f, outc = 0.f;
    #pragma unroll 1
    for (int jb = 0; jb < 16; ++jb) {
        float acc[8];
        #pragma unroll
        for (int j = 0; j < 8; ++j) acc[j] = sB1[jb*8 + j];
        #pragma unroll
        for (int kk = 0; kk < JOINT; ++kk) {
            const float4* w4 = reinterpret_cast<const float4*>(&sW[kk*128 + jb*8]);
            const float4 wa = w4[0];
            const float4 wb = w4[1];
            const float jv = jn[kk];
            acc[0] += jv*wa.x; acc[1] += jv*wa.y; acc[2] += jv*wa.z; acc[3] += jv*wa.w;
            acc[4] += jv*wb.x; acc[5] += jv*wb.y; acc[6] += jv*wb.z; acc[7] += jv*wb.w;
        }
        float part = 0.f;
        #pragma unroll
        for (int j = 0; j < 8; ++j) {
            const float xg = acc[j];
            const float g  = 0.5f * xg * (1.0f + erff(xg * 0.70710678118654752f));
            part += g * sW2[jb*8 + j];
        }
        if (jb < 8) outs += part; else outc += part;
    }
    outs += sup_b2[0];
    outc += con_b2[0];

    const float sv = softplusf(outs);
    const float cv = softplusf(outc);

    const float gate = vld ? act_in[nbp*NHYP + h2] : 0.f;
    svg[tid] = sv * gate;
    cvg[tid] = cv * gate;
    if (h == 0) sgate[pos*36 + s] = gate;
    __syncthreads();

    // ---- gated reduction + elementwise outputs (16 groups per block) ----
    if (tid < POS_PER_BLK*NHYP) {
        const int pos2 = tid >> 2, hh = tid & 3;
        const int base = pos2*144 + hh*36;
        float svs = 0.f, cvs = 0.f, mass = 0.f;
        for (int i = 0; i < 36; ++i) {
            svs  += svg[base + i];
            cvs  += cvg[base + i];
            mass += sgate[pos2*36 + i];
        }
        mass = fmaxf(mass, 1e-6f);
        const float support  = svs / mass;
        const float conflict = cvs / mass;
        const int bph = (blockIdx.x*POS_PER_BLK + pos2)*NHYP + hh;
        const float pd = drive[bph]  + support;
        const float pr = resist[bph] + conflict;
        float e = pd - pr + eml_bias[0];
        e = fminf(fmaxf(e, -3.f), 3.f);
        const float a = 1.f / (1.f + expf(-e));
        out[0*NOUT + bph] = support;
        out[1*NOUT + bph] = conflict;
        out[2*NOUT + bph] = pd;
        out[3*NOUT + bph] = pr;
        out[4*NOUT + bph] = e;
        out[5*NOUT + bph] = a;
        out[6*NOUT + bph] = mass;
    }
}

__global__ __launch_bounds__(256) void eml_scalars(
    const float* __restrict__ out_act, float* __restrict__ out3)
{
    __shared__ float red[4*3];
    float bl = 0.f, en = 0.f, ar = 0.f;
    for (int i = threadIdx.x; i < NOUT; i += 256) {
        const float a = out_act[i];
        bl += a;
        en += -(a*logf(a + 1e-8f) + (1.f - a)*logf(1.f - a + 1e-8f));
        ar += (a > 0.5f) ? 1.f : 0.f;
    }
    #pragma unroll
    for (int off = 32; off > 0; off >>= 1) {
        bl += __shfl_down(bl, off);
        en += __shfl_down(en, off);
        ar += __shfl_down(ar, off);
    }
    const int lane = threadIdx.x & 63, wid = threadIdx.x >> 6;
    if (lane == 0) { red[wid*3+0] = bl; red[wid*3+1] = en; red[wid*3+2] = ar; }
    __syncthreads();
    if (threadIdx.x == 0) {
        float b2 = 0.f, e2 = 0.f, a2 = 0.f;
        for (int w = 0; w < 4; ++w) { b2 += red[w*3]; e2 += red[w*3+1]; a2 += red[w*3+2]; }
        const float inv = 1.0f / (float)NOUT;
        out3[0] = b2*inv; out3[1] = e2*inv; out3[2] = a2*inv;
    }
}

extern "C" void kernel_launch(void* const* d_in, const int* in_sizes, int n_in,
                              void* d_out, int out_size, void* d_ws, size_t ws_size,
                              hipStream_t stream)
{
    (void)in_sizes; (void)n_in; (void)out_size; (void)d_ws; (void)ws_size;
    const float* hs      = (const float*)d_in[0];
    const float* act     = (const float*)d_in[1];
    const float* drv     = (const float*)d_in[2];
    const float* res     = (const float*)d_in[3];
    const float* rel     = (const float*)d_in[4];
    const float* lnw     = (const float*)d_in[5];
    const float* lnb     = (const float*)d_in[6];
    const float* sw1     = (const float*)d_in[7];
    const float* sb1     = (const float*)d_in[8];
    const float* sw2     = (const float*)d_in[9];
    const float* sb2     = (const float*)d_in[10];
    const float* cw1     = (const float*)d_in[11];
    const float* cb1     = (const float*)d_in[12];
    const float* cw2     = (const float*)d_in[13];
    const float* cb2     = (const float*)d_in[14];
    const float* ebias   = (const float*)d_in[15];
    float* out = (float*)d_out;

    eml_main<<<dim3(NBP/POS_PER_BLK), dim3(THREADS), 0, stream>>>(
        hs, act, drv, res, rel, lnw, lnb,
        sw1, sb1, sw2, sb2, cw1, cb1, cw2, cb2, ebias, out);
    eml_scalars<<<dim3(1), dim3(256), 0, stream>>>(out + 5*NOUT, out + 7*NOUT);
}

// Round 2
// 171.178 us; speedup vs baseline: 206.0386x; 206.0386x over previous
//
#include <hip/hip_runtime.h>
#include <hip/hip_bf16.h>
#include <math.h>

#define SIDE 48
#define PPOS (SIDE*SIDE)
#define NBATCH 2
#define NHYP 4
#define FD 32
#define RD 8
#define NJ 104
#define NBP (NBATCH*PPOS)       // 4608
#define NOUT (NBP*NHYP)         // 18432
#define POSB 4
#define THREADS 576             // 9 waves; 1:1 with 4*144 rows
#define NNB 18                  // 3 rows x 6 cols neighbor positions
#define NVEC 72                 // NNB*NHYP
#define SROW 97                 // 72 SB + 16 TA + 9 RC
#define SPAD 130                // bf16 elems per sOut row (stride 260B -> +1 bank/row)

__device__ __forceinline__ float bflo(unsigned u) { return __uint_as_float(u << 16); }
__device__ __forceinline__ float bfhi(unsigned u) { return __uint_as_float(u & 0xffff0000u); }
__device__ __forceinline__ unsigned packbf2(float a, float b) {
    unsigned ua = __float_as_uint(a), ub = __float_as_uint(b);
    unsigned ra = (ua + 0x7fffu + ((ua >> 16) & 1u)) >> 16;
    unsigned rb = (ub + 0x7fffu + ((ub >> 16) & 1u)) & 0xffff0000u;
    return ra | rb;
}
__device__ __forceinline__ float softplusf(float v) {
    return fmaxf(v, 0.f) + log1pf(expf(-fabsf(v)));
}
// gelu(x) ~= x * sigmoid(1.702 x); 1.702*log2(e) = 2.4554668
__device__ __forceinline__ float fast_gelu(float x) {
    float e = exp2f(-2.4554668f * x);
    return x * __builtin_amdgcn_rcpf(1.f + e);
}

__global__ __launch_bounds__(THREADS) void eml_main(
    const float* __restrict__ hs, const float* __restrict__ act_in,
    const float* __restrict__ drive, const float* __restrict__ resist,
    const float* __restrict__ rel, const float* __restrict__ ln_w,
    const float* __restrict__ ln_b,
    const float* __restrict__ sup_w1, const float* __restrict__ sup_b1,
    const float* __restrict__ sup_w2, const float* __restrict__ sup_b2,
    const float* __restrict__ con_w1, const float* __restrict__ con_b1,
    const float* __restrict__ con_w2, const float* __restrict__ con_b2,
    const float* __restrict__ eml_bias, float* __restrict__ out)
{
    // rows 0-31: B = W1'[32+i]-W1'[64+i]; 32-63: A = W1'[i]+W1'[64+i]; 64-71: C = W1'[96+i]
    __shared__ __hip_bfloat16 sW[NVEC * 128];       // 18432 B
    __shared__ float sS[128], sT[128], sw2v[128];   // 1536 B
    __shared__ float snb[NVEC * 36];                // 10368 B (pad 36 -> +4 banks/row)
    __shared__ float sact[NVEC];                    // 288 B
    __shared__ float sSt[NVEC], sSq[NVEC];          // 576 B
    __shared__ float sSr[9], sSqr[9];               // 72 B
    __shared__ float srel[9 * 8];                   // 288 B
    __shared__ __hip_bfloat16 sOutB[SROW * SPAD];   // 25220 B
    __shared__ float svg[THREADS], cvg[THREADS];    // 4608 B
    __shared__ float sscal[3];                      // b2_sup, b2_con, eml_bias

    const int tid = threadIdx.x;
    const int blk = blockIdx.x;
    const int b   = blk / (PPOS / POSB);
    const int rm  = blk % (PPOS / POSB);
    const int y   = rm / (SIDE / POSB);
    const int x0  = (rm % (SIDE / POSB)) * POSB;

    // ---- stage 0: fold LN into weights; derive A/B/C (bf16), S, T, w2 ----
    #define W1X(kk, j) ((j) < 64 ? sup_w1[(kk)*64 + (j)] : con_w1[(kk)*64 + (j) - 64])
    for (int p = 0; p < 16; ++p) {
        int u = p * THREADS + tid;            // 16*576 == 9216 exactly
        int r = u >> 7, j = u & 127;
        float val;
        if (r < 32)      val = ln_w[32+r] * W1X(32+r, j) - ln_w[64+r] * W1X(64+r, j);
        else if (r < 64) { int i = r - 32; val = ln_w[i] * W1X(i, j) + ln_w[64+i] * W1X(64+i, j); }
        else             { int i = r - 64; val = ln_w[96+i] * W1X(96+i, j); }
        sW[u] = __float2bfloat16(val);
    }
    if (tid < 128) {
        float S = 0.f, T = 0.f;
        for (int kk = 0; kk < NJ; ++kk) {
            float w = W1X(kk, tid);
            S += ln_w[kk] * w;
            T += ln_b[kk] * w;
        }
        sS[tid] = S;
        sT[tid] = T + (tid < 64 ? sup_b1[tid] : con_b1[tid - 64]);
        sw2v[tid] = (tid < 64 ? sup_w2[tid] : con_w2[tid - 64]);
    }

    // ---- stage 1: stage 72 neighbor vectors + sums + activations ----
    {
        int vec = tid >> 3, q = tid & 7;      // 72 vecs x 8 threads
        int nb = vec >> 2, h = vec & 3;
        int yy = y + nb / 6 - 1, xx = x0 + nb % 6 - 1;
        bool vld = (yy >= 0) && (yy < SIDE) && (xx >= 0) && (xx < SIDE);
        int npos = b * PPOS + yy * SIDE + xx;
        float4 v = make_float4(0.f, 0.f, 0.f, 0.f);
        if (vld) v = *reinterpret_cast<const float4*>(&hs[((size_t)npos * NHYP + h) * FD + q * 4]);
        float* dst = &snb[vec * 36 + q * 4];
        dst[0] = v.x; dst[1] = v.y; dst[2] = v.z; dst[3] = v.w;
        float s  = v.x + v.y + v.z + v.w;
        float sq = v.x*v.x + v.y*v.y + v.z*v.z + v.w*v.w;
        s  += __shfl_xor(s, 1);  sq += __shfl_xor(sq, 1);
        s  += __shfl_xor(s, 2);  sq += __shfl_xor(sq, 2);
        s  += __shfl_xor(s, 4);  sq += __shfl_xor(sq, 4);
        if (q == 0) {
            sSt[vec] = s; sSq[vec] = sq;
            sact[vec] = vld ? act_in[npos * NHYP + h] : 0.f;
        }
    }
    if (tid < 72) srel[tid] = rel[tid];
    if (tid < 9) {
        float s = 0.f, sq = 0.f;
        #pragma unroll
        for (int i = 0; i < 8; ++i) { float v = rel[tid * 8 + i]; s += v; sq += v * v; }
        sSr[tid] = s; sSqr[tid] = sq;
    }
    if (tid == 0) { sscal[0] = sup_b2[0]; sscal[1] = con_b2[0]; sscal[2] = eml_bias[0]; }
    __syncthreads();

    // ---- stage 2: partial GEMMs -> sOutB (97 rows x 128, bf16) ----
    for (int p = 0; p < 3; ++p) {
        int t = p * THREADS + tid;
        if (t < SROW * 16) {
            int vec = t >> 4, jo = t & 15;
            const float* vsrc; int wr0, iters;
            if (vec < 72)      { vsrc = &snb[vec * 36]; wr0 = 0; iters = 32; }
            else if (vec < 88) { int q = vec - 72; int pos = q >> 2, h = q & 3;
                                 vsrc = &snb[((7 + pos) * 4 + h) * 36]; wr0 = 32; iters = 32; }
            else               { vsrc = &srel[(vec - 88) * 8]; wr0 = 64; iters = 8; }
            float a0=0,a1=0,a2=0,a3=0,a4=0,a5=0,a6=0,a7=0;
            for (int i = 0; i < iters; ++i) {
                float v = vsrc[i];
                uint4 w = *reinterpret_cast<const uint4*>(&sW[(wr0 + i) * 128 + jo * 8]);
                a0 += v * bflo(w.x); a1 += v * bfhi(w.x);
                a2 += v * bflo(w.y); a3 += v * bfhi(w.y);
                a4 += v * bflo(w.z); a5 += v * bfhi(w.z);
                a6 += v * bflo(w.w); a7 += v * bfhi(w.w);
            }
            unsigned* dst = reinterpret_cast<unsigned*>(&sOutB[vec * SPAD + jo * 8]);
            dst[0] = packbf2(a0, a1); dst[1] = packbf2(a2, a3);
            dst[2] = packbf2(a4, a5); dst[3] = packbf2(a6, a7);
        }
    }
    __syncthreads();

    // ---- stage 3: per-row epilogue (thread = row) ----
    {
        int pos = tid / 144, r = tid % 144;
        int h = r / 36, s = r % 36, k = s >> 2, h2 = s & 3;
        int nb = (k / 3) * 6 + pos + (k % 3);
        float gate = sact[nb * 4 + h2];
        float sv = 0.f, cv = 0.f;
        if (gate > 0.f) {
            int ctr = (7 + pos) * 4 + h;
            float St = sSt[ctr], Sqt = sSq[ctr], Sqs = sSq[nb * 4 + h2];
            const float* tv = &snb[ctr * 36];
            const float* sr = &snb[(nb * 4 + h2) * 36];
            float dot = 0.f;
            #pragma unroll
            for (int i = 0; i < FD; ++i) dot += tv[i] * sr[i];
            float mu   = (2.f * St + sSr[k]) * (1.f / NJ);
            float ssum = 2.f * Sqt + 2.f * Sqs - 2.f * dot + sSqr[k];
            float rinv = rsqrtf(ssum * (1.f / NJ) - mu * mu + 1e-5f);
            const unsigned* ta = reinterpret_cast<const unsigned*>(&sOutB[(72 + pos * 4 + h) * SPAD]);
            const unsigned* sb = reinterpret_cast<const unsigned*>(&sOutB[(nb * 4 + h2) * SPAD]);
            const unsigned* rc = reinterpret_cast<const unsigned*>(&sOutB[(88 + k) * SPAD]);
            float outs = 0.f, outc = 0.f;
            #pragma unroll 8
            for (int jp = 0; jp < 64; ++jp) {
                unsigned ua = ta[jp], ub = sb[jp], uc = rc[jp];
                float d0 = bflo(ua) + bflo(ub) + bflo(uc);
                float d1 = bfhi(ua) + bfhi(ub) + bfhi(uc);
                int j0 = 2 * jp, j1 = j0 + 1;
                float p0 = (d0 - mu * sS[j0]) * rinv + sT[j0];
                float p1 = (d1 - mu * sS[j1]) * rinv + sT[j1];
                float acc = fast_gelu(p0) * sw2v[j0] + fast_gelu(p1) * sw2v[j1];
                if (jp < 32) outs += acc; else outc += acc;
            }
            sv = softplusf(outs + sscal[0]);
            cv = softplusf(outc + sscal[1]);
        }
        svg[tid] = sv * gate;
        cvg[tid] = cv * gate;
    }
    __syncthreads();

    // ---- stage 4: gated reduction + outputs ----
    if (tid < POSB * NHYP) {
        int pos = tid >> 2, hh = tid & 3;
        int base = pos * 144 + hh * 36;
        float svs = 0.f, cvs = 0.f, mass = 0.f;
        #pragma unroll
        for (int i = 0; i < 36; ++i) { svs += svg[base + i]; cvs += cvg[base + i]; }
        #pragma unroll
        for (int k = 0; k < 9; ++k) {
            int nb = (k / 3) * 6 + pos + (k % 3);
            #pragma unroll
            for (int h2 = 0; h2 < 4; ++h2) mass += sact[nb * 4 + h2];
        }
        mass = fmaxf(mass, 1e-6f);
        float support  = svs / mass;
        float conflict = cvs / mass;
        int bph = (b * PPOS + y * SIDE + x0 + pos) * NHYP + hh;
        float pd = drive[bph]  + support;
        float pr = resist[bph] + conflict;
        float e = pd - pr + sscal[2];
        e = fminf(fmaxf(e, -3.f), 3.f);
        float a = 1.f / (1.f + expf(-e));
        out[0 * NOUT + bph] = support;
        out[1 * NOUT + bph] = conflict;
        out[2 * NOUT + bph] = pd;
        out[3 * NOUT + bph] = pr;
        out[4 * NOUT + bph] = e;
        out[5 * NOUT + bph] = a;
        out[6 * NOUT + bph] = mass;
    }
}

__global__ __launch_bounds__(256) void eml_scalars(
    const float* __restrict__ out_act, float* __restrict__ out3)
{
    __shared__ float red[4 * 3];
    float bl = 0.f, en = 0.f, ar = 0.f;
    for (int i = threadIdx.x; i < NOUT; i += 256) {
        const float a = out_act[i];
        bl += a;
        en += -(a * logf(a + 1e-8f) + (1.f - a) * logf(1.f - a + 1e-8f));
        ar += (a > 0.5f) ? 1.f : 0.f;
    }
    #pragma unroll
    for (int off = 32; off > 0; off >>= 1) {
        bl += __shfl_down(bl, off);
        en += __shfl_down(en, off);
        ar += __shfl_down(ar, off);
    }
    const int lane = threadIdx.x & 63, wid = threadIdx.x >> 6;
    if (lane == 0) { red[wid*3+0] = bl; red[wid*3+1] = en; red[wid*3+2] = ar; }
    __syncthreads();
    if (threadIdx.x == 0) {
        float b2 = 0.f, e2 = 0.f, a2 = 0.f;
        for (int w = 0; w < 4; ++w) { b2 += red[w*3]; e2 += red[w*3+1]; a2 += red[w*3+2]; }
        const float inv = 1.0f / (float)NOUT;
        out3[0] = b2 * inv; out3[1] = e2 * inv; out3[2] = a2 * inv;
    }
}

extern "C" void kernel_launch(void* const* d_in, const int* in_sizes, int n_in,
                              void* d_out, int out_size, void* d_ws, size_t ws_size,
                              hipStream_t stream)
{
    (void)in_sizes; (void)n_in; (void)out_size; (void)d_ws; (void)ws_size;
    const float* hs    = (const float*)d_in[0];
    const float* act   = (const float*)d_in[1];
    const float* drv   = (const float*)d_in[2];
    const float* res   = (const float*)d_in[3];
    const float* rel   = (const float*)d_in[4];
    const float* lnw   = (const float*)d_in[5];
    const float* lnb   = (const float*)d_in[6];
    const float* sw1   = (const float*)d_in[7];
    const float* sb1   = (const float*)d_in[8];
    const float* sw2   = (const float*)d_in[9];
    const float* sb2   = (const float*)d_in[10];
    const float* cw1   = (const float*)d_in[11];
    const float* cb1   = (const float*)d_in[12];
    const float* cw2   = (const float*)d_in[13];
    const float* cb2   = (const float*)d_in[14];
    const float* ebias = (const float*)d_in[15];
    float* out = (float*)d_out;

    eml_main<<<dim3(NBP / POSB), dim3(THREADS), 0, stream>>>(
        hs, act, drv, res, rel, lnw, lnb,
        sw1, sb1, sw2, sb2, cw1, cb1, cw2, cb2, ebias, out);
    eml_scalars<<<dim3(1), dim3(256), 0, stream>>>(out + 5 * NOUT, out + 7 * NOUT);
}

// Round 3
// 136.033 us; speedup vs baseline: 259.2705x; 1.2584x over previous
//
#include <hip/hip_runtime.h>
#include <hip/hip_bf16.h>
#include <math.h>

#define SIDE 48
#define PPOS (SIDE*SIDE)
#define NBATCH 2
#define NHYP 4
#define FD 32
#define RD 8
#define NJ 104
#define NBP (NBATCH*PPOS)       // 4608
#define NOUT (NBP*NHYP)         // 18432
#define POSB 4
#define THREADS 576
#define NVEC 72
#define NBLK (NBP/POSB)         // 1152
// d_ws float offsets
#define WS_SR   16
#define WS_SQR  28
#define WS_SC   40
#define WS_ROWS 64              // 12 rows x 128 bf16 = 768 floats (rc0..8, S, T, w2)
#define WS_W    832             // 72 rows x 128 bf16 = 4608 floats
#define WS_PART 5504            // 3 x NBLK floats

__device__ __forceinline__ float bflo(unsigned u) { return __uint_as_float(u << 16); }
__device__ __forceinline__ float bfhi(unsigned u) { return __uint_as_float(u & 0xffff0000u); }
__device__ __forceinline__ unsigned packbf2(float a, float b) {
    unsigned ua = __float_as_uint(a), ub = __float_as_uint(b);
    unsigned ra = (ua + 0x7fffu + ((ua >> 16) & 1u)) >> 16;
    unsigned rb = (ub + 0x7fffu + ((ub >> 16) & 1u)) & 0xffff0000u;
    return ra | rb;
}
__device__ __forceinline__ float softplusf(float v) {
    return fmaxf(v, 0.f) + log1pf(expf(-fabsf(v)));
}
__device__ __forceinline__ float fast_gelu(float x) {
    float e = exp2f(-2.4554668f * x);
    return x * __builtin_amdgcn_rcpf(1.f + e);
}

#define W1X(kk, j) ((j) < 64 ? sup_w1[(kk)*64 + (j)] : con_w1[(kk)*64 + (j) - 64])

// ---------------- pre-kernel: fold weights once ----------------
__global__ __launch_bounds__(576) void eml_fold(
    const float* __restrict__ rel, const float* __restrict__ ln_w, const float* __restrict__ ln_b,
    const float* __restrict__ sup_w1, const float* __restrict__ sup_b1,
    const float* __restrict__ sup_w2, const float* __restrict__ sup_b2,
    const float* __restrict__ con_w1, const float* __restrict__ con_b1,
    const float* __restrict__ con_w2, const float* __restrict__ con_b2,
    const float* __restrict__ eml_bias, float* __restrict__ ws)
{
    const int tid = threadIdx.x;
    __hip_bfloat16* wsW = reinterpret_cast<__hip_bfloat16*>(ws + WS_W);
    __hip_bfloat16* wsR = reinterpret_cast<__hip_bfloat16*>(ws + WS_ROWS);
    // rows 0-31: B = lnw*W1[src] - lnw*W1[diff]; 32-63: A = lnw*W1[tgt] + lnw*W1[diff]; 64-71: C
    for (int p = 0; p < 16; ++p) {
        int u = p * 576 + tid;
        int r = u >> 7, j = u & 127;
        float val;
        if (r < 32)      val = ln_w[32+r]*W1X(32+r,j) - ln_w[64+r]*W1X(64+r,j);
        else if (r < 64) { int i = r-32; val = ln_w[i]*W1X(i,j) + ln_w[64+i]*W1X(64+i,j); }
        else             { int i = r-64; val = ln_w[96+i]*W1X(96+i,j); }
        wsW[u] = __float2bfloat16(val);
    }
    for (int u = tid; u < 9*128; u += 576) {      // rc[k][j] = rel_k @ C
        int k = u >> 7, j = u & 127;
        float a = 0.f;
        #pragma unroll
        for (int i = 0; i < 8; ++i) a += rel[k*8+i] * ln_w[96+i] * W1X(96+i, j);
        wsR[u] = __float2bfloat16(a);
    }
    if (tid < 128) {
        float S = 0.f, T = 0.f;
        for (int kk = 0; kk < NJ; ++kk) { float w = W1X(kk, tid); S += ln_w[kk]*w; T += ln_b[kk]*w; }
        wsR[9*128 + tid]  = __float2bfloat16(S);
        wsR[10*128 + tid] = __float2bfloat16(T + (tid < 64 ? sup_b1[tid] : con_b1[tid-64]));
        wsR[11*128 + tid] = __float2bfloat16(tid < 64 ? sup_w2[tid] : con_w2[tid-64]);
    }
    if (tid < 9) {
        float s = 0.f, sq = 0.f;
        #pragma unroll
        for (int i = 0; i < 8; ++i) { float v = rel[tid*8+i]; s += v; sq += v*v; }
        ws[WS_SR+tid] = s; ws[WS_SQR+tid] = sq;
    }
    if (tid == 0) { ws[WS_SC] = sup_b2[0]; ws[WS_SC+1] = con_b2[0]; ws[WS_SC+2] = eml_bias[0]; }
}

// ---------------- main kernel ----------------
__global__ __launch_bounds__(THREADS) void eml_main(
    const float* __restrict__ hs, const float* __restrict__ act_in,
    const float* __restrict__ drive, const float* __restrict__ resist,
    float* __restrict__ out, float* __restrict__ ws)
{
    __shared__ __align__(16) __hip_bfloat16 sW[NVEC*128];   // 18432 B
    __shared__ __align__(16) unsigned sOutB[100*66];        // 26400 B (row stride 66 dw = 132 bf16)
    __shared__ __align__(8)  __hip_bfloat16 snb[NVEC*34];   // 4896 B
    __shared__ float sact[NVEC];                            // 288 B
    __shared__ float sSt[NVEC], sSq[NVEC];                  // 576 B
    __shared__ float sSr[9], sSqr[9], sscal[3];             // 84 B
    __shared__ unsigned svcv[THREADS];                      // 2304 B

    const int tid = threadIdx.x;
    const int blk = blockIdx.x;
    const int b   = blk / (PPOS / POSB);
    const int rm  = blk % (PPOS / POSB);
    const int y   = rm / (SIDE / POSB);
    const int x0  = (rm % (SIDE / POSB)) * POSB;

    // ---- stage 1 global loads (issued first) ----
    const int vec = tid >> 3, q = tid & 7;       // 72 vecs x 8 threads
    const int nb1 = vec >> 2, h1 = vec & 3;
    const int yy = y + nb1/6 - 1, xx = x0 + nb1%6 - 1;
    const bool vld = (yy >= 0) && (yy < SIDE) && (xx >= 0) && (xx < SIDE);
    const int npos = b*PPOS + yy*SIDE + xx;
    float4 v = make_float4(0.f, 0.f, 0.f, 0.f);
    if (vld) v = *reinterpret_cast<const float4*>(&hs[((size_t)npos*NHYP + h1)*FD + q*4]);

    // ---- stage folded weights -> LDS ----
    {
        const uint4* gsrc = reinterpret_cast<const uint4*>(ws + WS_W);
        uint4* ldst = reinterpret_cast<uint4*>(sW);
        ldst[tid*2]   = gsrc[tid*2];
        ldst[tid*2+1] = gsrc[tid*2+1];
    }
    {
        const unsigned* gsrc = reinterpret_cast<const unsigned*>(ws + WS_ROWS);
        for (int u = tid; u < 12*64; u += THREADS) {
            int r = u >> 6, d = u & 63;
            sOutB[(88+r)*66 + d] = gsrc[u];
        }
    }
    if (tid < 9) { sSr[tid] = ws[WS_SR+tid]; sSqr[tid] = ws[WS_SQR+tid]; }
    if (tid < 3) sscal[tid] = ws[WS_SC+tid];

    // ---- snb (bf16) + per-vector sums + gates ----
    {
        unsigned* drow = reinterpret_cast<unsigned*>(&snb[vec*34]);
        drow[q*2]   = packbf2(v.x, v.y);
        drow[q*2+1] = packbf2(v.z, v.w);
        float s  = v.x + v.y + v.z + v.w;
        float sq = v.x*v.x + v.y*v.y + v.z*v.z + v.w*v.w;
        s += __shfl_xor(s, 1); sq += __shfl_xor(sq, 1);
        s += __shfl_xor(s, 2); sq += __shfl_xor(sq, 2);
        s += __shfl_xor(s, 4); sq += __shfl_xor(sq, 4);
        if (q == 0) {
            sSt[vec] = s; sSq[vec] = sq;
            sact[vec] = vld ? act_in[npos*NHYP + h1] : 0.f;
        }
    }
    __syncthreads();

    // ---- stage 2: 88 vecs x 32-dot x 128 cols -> sOutB bf16 ----
    for (int p = 0; p < 3; ++p) {
        int t = p*THREADS + tid;
        if (t < 88*16) {
            int sv = t >> 4, jo = t & 15;
            int srow, wr0;
            if (sv < 72) { srow = sv; wr0 = 0; }
            else { int qq = sv - 72; srow = (7 + (qq >> 2))*4 + (qq & 3); wr0 = 32; }
            const unsigned* vsrc = reinterpret_cast<const unsigned*>(&snb[srow*34]);
            float a0=0,a1=0,a2=0,a3=0,a4=0,a5=0,a6=0,a7=0;
            #pragma unroll
            for (int i2 = 0; i2 < 16; ++i2) {
                unsigned vv = vsrc[i2];
                float v0 = bflo(vv), v1 = bfhi(vv);
                uint4 w0 = *reinterpret_cast<const uint4*>(&sW[(wr0 + 2*i2)*128 + jo*8]);
                a0 += v0*bflo(w0.x); a1 += v0*bfhi(w0.x);
                a2 += v0*bflo(w0.y); a3 += v0*bfhi(w0.y);
                a4 += v0*bflo(w0.z); a5 += v0*bfhi(w0.z);
                a6 += v0*bflo(w0.w); a7 += v0*bfhi(w0.w);
                uint4 w1 = *reinterpret_cast<const uint4*>(&sW[(wr0 + 2*i2 + 1)*128 + jo*8]);
                a0 += v1*bflo(w1.x); a1 += v1*bfhi(w1.x);
                a2 += v1*bflo(w1.y); a3 += v1*bfhi(w1.y);
                a4 += v1*bflo(w1.z); a5 += v1*bfhi(w1.z);
                a6 += v1*bflo(w1.w); a7 += v1*bfhi(w1.w);
            }
            unsigned* dst = &sOutB[sv*66 + jo*4];
            *reinterpret_cast<uint2*>(dst)     = make_uint2(packbf2(a0,a1), packbf2(a2,a3));
            *reinterpret_cast<uint2*>(dst + 2) = make_uint2(packbf2(a4,a5), packbf2(a6,a7));
        }
    }
    __syncthreads();

    // ---- stage 3: per-row epilogue ----
    {
        const int pos = tid / 144, r = tid % 144;
        const int hh = r / 36, s = r % 36, k = s >> 2, h2 = s & 3;
        const int nbr  = (k/3)*6 + pos + (k%3);
        const int srow = nbr*4 + h2;
        const float gate = sact[srow];
        float svv = 0.f, cvv = 0.f;
        if (gate > 0.f) {
            const int crow = (7 + pos)*4 + hh;
            const unsigned* tv = reinterpret_cast<const unsigned*>(&snb[crow*34]);
            const unsigned* sr = reinterpret_cast<const unsigned*>(&snb[srow*34]);
            float dot = 0.f;
            #pragma unroll
            for (int i2 = 0; i2 < 16; ++i2) {
                unsigned ua = tv[i2], ub = sr[i2];
                dot += bflo(ua)*bflo(ub) + bfhi(ua)*bfhi(ub);
            }
            const float mu   = (2.f*sSt[crow] + sSr[k]) * (1.f/NJ);
            const float ssum = 2.f*sSq[crow] + 2.f*sSq[srow] - 2.f*dot + sSqr[k];
            const float rinv = rsqrtf(ssum*(1.f/NJ) - mu*mu + 1e-5f);
            const float beta = -mu*rinv;
            const uint2* pa = reinterpret_cast<const uint2*>(&sOutB[(72 + pos*4 + hh)*66]);
            const uint2* pb = reinterpret_cast<const uint2*>(&sOutB[srow*66]);
            const uint2* pc = reinterpret_cast<const uint2*>(&sOutB[(88 + k)*66]);
            const uint2* pS = reinterpret_cast<const uint2*>(&sOutB[97*66]);
            const uint2* pT = reinterpret_cast<const uint2*>(&sOutB[98*66]);
            const uint2* pW = reinterpret_cast<const uint2*>(&sOutB[99*66]);
            float outs = 0.f, outc = 0.f;
            #pragma unroll 4
            for (int jq = 0; jq < 32; ++jq) {
                uint2 ua = pa[jq], ub = pb[jq], uc = pc[jq];
                uint2 uS = pS[jq], uT = pT[jq], uW = pW[jq];
                float d, pv, accv = 0.f;
                d  = bflo(ua.x) + bflo(ub.x) + bflo(uc.x);
                pv = fmaf(rinv, d, fmaf(beta, bflo(uS.x), bflo(uT.x)));
                accv += fast_gelu(pv) * bflo(uW.x);
                d  = bfhi(ua.x) + bfhi(ub.x) + bfhi(uc.x);
                pv = fmaf(rinv, d, fmaf(beta, bfhi(uS.x), bfhi(uT.x)));
                accv += fast_gelu(pv) * bfhi(uW.x);
                d  = bflo(ua.y) + bflo(ub.y) + bflo(uc.y);
                pv = fmaf(rinv, d, fmaf(beta, bflo(uS.y), bflo(uT.y)));
                accv += fast_gelu(pv) * bflo(uW.y);
                d  = bfhi(ua.y) + bfhi(ub.y) + bfhi(uc.y);
                pv = fmaf(rinv, d, fmaf(beta, bfhi(uS.y), bfhi(uT.y)));
                accv += fast_gelu(pv) * bfhi(uW.y);
                if (jq < 16) outs += accv; else outc += accv;
            }
            svv = softplusf(outs + sscal[0]);
            cvv = softplusf(outc + sscal[1]);
        }
        svcv[tid] = packbf2(svv*gate, cvv*gate);
    }
    __syncthreads();

    // ---- stage 4: gated reduction + outputs + per-block scalar partials ----
    if (tid < 64) {
        const int pos4 = tid >> 4, hh4 = (tid >> 2) & 3, qq = tid & 3;
        float svs = 0.f, cvs = 0.f, mass = 0.f;
        #pragma unroll
        for (int i = 0; i < 9; ++i) {
            int s = qq*9 + i;
            unsigned pp = svcv[pos4*144 + hh4*36 + s];
            svs += bflo(pp); cvs += bfhi(pp);
            int kk = s >> 2, h2 = s & 3;
            int nbr = (kk/3)*6 + pos4 + (kk%3);
            mass += sact[nbr*4 + h2];
        }
        svs += __shfl_xor(svs, 1); cvs += __shfl_xor(cvs, 1); mass += __shfl_xor(mass, 1);
        svs += __shfl_xor(svs, 2); cvs += __shfl_xor(cvs, 2); mass += __shfl_xor(mass, 2);
        float bl = 0.f, en = 0.f, ar = 0.f;
        if (qq == 0) {
            mass = fmaxf(mass, 1e-6f);
            const float support  = svs / mass;
            const float conflict = cvs / mass;
            const int bph = (b*PPOS + y*SIDE + x0 + pos4)*NHYP + hh4;
            const float pd = drive[bph]  + support;
            const float pr = resist[bph] + conflict;
            float e = fminf(fmaxf(pd - pr + sscal[2], -3.f), 3.f);
            const float a = 1.f / (1.f + expf(-e));
            out[0*NOUT + bph] = support;
            out[1*NOUT + bph] = conflict;
            out[2*NOUT + bph] = pd;
            out[3*NOUT + bph] = pr;
            out[4*NOUT + bph] = e;
            out[5*NOUT + bph] = a;
            out[6*NOUT + bph] = mass;
            bl = a;
            en = -(a*logf(a + 1e-8f) + (1.f - a)*logf(1.f - a + 1e-8f));
            ar = (a > 0.5f) ? 1.f : 0.f;
        }
        #pragma unroll
        for (int off = 32; off > 0; off >>= 1) {
            bl += __shfl_down(bl, off); en += __shfl_down(en, off); ar += __shfl_down(ar, off);
        }
        if (tid == 0) {
            ws[WS_PART + blk]          = bl;
            ws[WS_PART + NBLK + blk]   = en;
            ws[WS_PART + 2*NBLK + blk] = ar;
        }
    }
}

// ---------------- final: reduce per-block partials ----------------
__global__ __launch_bounds__(256) void eml_final(const float* __restrict__ ws, float* __restrict__ out3)
{
    __shared__ float red[4*3];
    float bl = 0.f, en = 0.f, ar = 0.f;
    for (int i = threadIdx.x; i < NBLK; i += 256) {
        bl += ws[WS_PART + i];
        en += ws[WS_PART + NBLK + i];
        ar += ws[WS_PART + 2*NBLK + i];
    }
    #pragma unroll
    for (int off = 32; off > 0; off >>= 1) {
        bl += __shfl_down(bl, off); en += __shfl_down(en, off); ar += __shfl_down(ar, off);
    }
    const int lane = threadIdx.x & 63, wid = threadIdx.x >> 6;
    if (lane == 0) { red[wid*3] = bl; red[wid*3+1] = en; red[wid*3+2] = ar; }
    __syncthreads();
    if (threadIdx.x == 0) {
        float b2 = 0.f, e2 = 0.f, a2 = 0.f;
        for (int w = 0; w < 4; ++w) { b2 += red[w*3]; e2 += red[w*3+1]; a2 += red[w*3+2]; }
        const float inv = 1.0f / (float)NOUT;
        out3[0] = b2*inv; out3[1] = e2*inv; out3[2] = a2*inv;
    }
}

extern "C" void kernel_launch(void* const* d_in, const int* in_sizes, int n_in,
                              void* d_out, int out_size, void* d_ws, size_t ws_size,
                              hipStream_t stream)
{
    (void)in_sizes; (void)n_in; (void)out_size; (void)ws_size;
    const float* hs    = (const float*)d_in[0];
    const float* act   = (const float*)d_in[1];
    const float* drv   = (const float*)d_in[2];
    const float* res   = (const float*)d_in[3];
    const float* rel   = (const float*)d_in[4];
    const float* lnw   = (const float*)d_in[5];
    const float* lnb   = (const float*)d_in[6];
    const float* sw1   = (const float*)d_in[7];
    const float* sb1   = (const float*)d_in[8];
    const float* sw2   = (const float*)d_in[9];
    const float* sb2   = (const float*)d_in[10];
    const float* cw1   = (const float*)d_in[11];
    const float* cb1   = (const float*)d_in[12];
    const float* cw2   = (const float*)d_in[13];
    const float* cb2   = (const float*)d_in[14];
    const float* ebias = (const float*)d_in[15];
    float* out = (float*)d_out;
    float* ws  = (float*)d_ws;

    eml_fold<<<dim3(1), dim3(576), 0, stream>>>(
        rel, lnw, lnb, sw1, sb1, sw2, sb2, cw1, cb1, cw2, cb2, ebias, ws);
    eml_main<<<dim3(NBLK), dim3(THREADS), 0, stream>>>(hs, act, drv, res, out, ws);
    eml_final<<<dim3(1), dim3(256), 0, stream>>>(ws, out + 7*NOUT);
}

// Round 4
// 109.332 us; speedup vs baseline: 322.5901x; 1.2442x over previous
//
#include <hip/hip_runtime.h>
#include <hip/hip_bf16.h>
#include <math.h>

#define SIDE 48
#define PPOS (SIDE*SIDE)
#define NBATCH 2
#define NHYP 4
#define FD 32
#define RD 8
#define NJ 104
#define NBP (NBATCH*PPOS)       // 4608
#define NOUT (NBP*NHYP)         // 18432
#define POSB 4
#define THREADS 576
#define NBLK (NBP/POSB)         // 1152
// d_ws float(dword) offsets
#define WS_SR   16
#define WS_SQR  28
#define WS_SC   40
#define WS_ROWS 64              // 12 rows x 64 dw (bf16-pair packed): rc0..8, S, T, w2
#define WS_WBF  832             // 2048 dw: Wb B-fragments (8 ntiles x 64 lanes x 4 dw)
#define WS_WAF  2880            // 2048 dw: Wa B-fragments
#define WS_PART 4928            // 3 x NBLK floats

typedef __attribute__((ext_vector_type(8))) short short8;
typedef __attribute__((ext_vector_type(4))) float f32x4;
union U8 { uint4 u4; short8 s8; };

__device__ __forceinline__ float bflo(unsigned u) { return __uint_as_float(u << 16); }
__device__ __forceinline__ float bfhi(unsigned u) { return __uint_as_float(u & 0xffff0000u); }
__device__ __forceinline__ unsigned packbf2(float a, float b) {
    unsigned ua = __float_as_uint(a), ub = __float_as_uint(b);
    unsigned ra = (ua + 0x7fffu + ((ua >> 16) & 1u)) >> 16;
    unsigned rb = (ub + 0x7fffu + ((ub >> 16) & 1u)) & 0xffff0000u;
    return ra | rb;
}
__device__ __forceinline__ float softplusf(float v) {
    return fmaxf(v, 0.f) + log1pf(expf(-fabsf(v)));
}
__device__ __forceinline__ float fast_gelu(float x) {
    float e = exp2f(-2.4554668f * x);
    return x * __builtin_amdgcn_rcpf(1.f + e);
}

#define W1X(kk, j) ((j) < 64 ? sup_w1[(kk)*64 + (j)] : con_w1[(kk)*64 + (j) - 64])

// ---------------- pre-kernel: fold weights once ----------------
__global__ __launch_bounds__(576) void eml_fold(
    const float* __restrict__ rel, const float* __restrict__ ln_w, const float* __restrict__ ln_b,
    const float* __restrict__ sup_w1, const float* __restrict__ sup_b1,
    const float* __restrict__ sup_w2, const float* __restrict__ sup_b2,
    const float* __restrict__ con_w1, const float* __restrict__ con_b1,
    const float* __restrict__ con_w2, const float* __restrict__ con_b2,
    const float* __restrict__ eml_bias, float* __restrict__ ws)
{
    const int tid = threadIdx.x;
    unsigned* wsd = reinterpret_cast<unsigned*>(ws);
    __hip_bfloat16* wsR = reinterpret_cast<__hip_bfloat16*>(ws + WS_ROWS);

    // B-fragment layouts for MFMA: lane l holds W^T[col][k] pairs, k0=(l>>4)*8+2j
    for (int u = tid; u < 2*2048; u += 576) {
        int sel = u >> 11, v2 = u & 2047;
        int n = v2 >> 8, l = (v2 >> 2) & 63, j = v2 & 3;
        int k0 = (l >> 4)*8 + 2*j, col = n*16 + (l & 15);
        float lo, hi;
        if (sel == 0) {   // Wb (src): lnw[32+k]W1[32+k] - lnw[64+k]W1[64+k]
            lo = ln_w[32+k0]*W1X(32+k0,col)   - ln_w[64+k0]*W1X(64+k0,col);
            hi = ln_w[32+k0+1]*W1X(32+k0+1,col) - ln_w[64+k0+1]*W1X(64+k0+1,col);
        } else {          // Wa (tgt): lnw[k]W1[k] + lnw[64+k]W1[64+k]
            lo = ln_w[k0]*W1X(k0,col)     + ln_w[64+k0]*W1X(64+k0,col);
            hi = ln_w[k0+1]*W1X(k0+1,col) + ln_w[64+k0+1]*W1X(64+k0+1,col);
        }
        wsd[(sel ? WS_WAF : WS_WBF) + v2] = packbf2(lo, hi);
    }
    // rc rows: rel_k @ C
    for (int u = tid; u < 9*128; u += 576) {
        int k = u >> 7, j = u & 127;
        float a = 0.f;
        #pragma unroll
        for (int i = 0; i < 8; ++i) a += rel[k*8+i] * ln_w[96+i] * W1X(96+i, j);
        wsR[u] = __float2bfloat16(a);
    }
    if (tid < 128) {
        float S = 0.f, T = 0.f;
        for (int kk = 0; kk < NJ; ++kk) { float w = W1X(kk, tid); S += ln_w[kk]*w; T += ln_b[kk]*w; }
        wsR[9*128 + tid]  = __float2bfloat16(S);
        wsR[10*128 + tid] = __float2bfloat16(T + (tid < 64 ? sup_b1[tid] : con_b1[tid-64]));
        wsR[11*128 + tid] = __float2bfloat16(tid < 64 ? sup_w2[tid] : con_w2[tid-64]);
    }
    if (tid < 9) {
        float s = 0.f, sq = 0.f;
        #pragma unroll
        for (int i = 0; i < 8; ++i) { float v = rel[tid*8+i]; s += v; sq += v*v; }
        ws[WS_SR+tid] = s; ws[WS_SQR+tid] = sq;
    }
    if (tid == 0) { ws[WS_SC] = sup_b2[0]; ws[WS_SC+1] = con_b2[0]; ws[WS_SC+2] = eml_bias[0]; }
}

// ---------------- main kernel ----------------
__global__ __launch_bounds__(THREADS) void eml_main(
    const float* __restrict__ hs, const float* __restrict__ act_in,
    const float* __restrict__ drive, const float* __restrict__ resist,
    float* __restrict__ out, float* __restrict__ ws)
{
    // sOutB rows: 0-71 src@Wb, 72-87 tgt@Wa, 88-96 rc[k], 97 S, 98 T, 99 w2
    __shared__ __align__(16) unsigned sOutB[100*68];        // 27200 B (stride 272B)
    __shared__ __align__(16) __hip_bfloat16 snb[80*40];     // 6400 B (stride 80B; rows 72-79 zero)
    __shared__ __align__(16) float sdot[80*20];             // 6400 B [s][c]
    __shared__ float sact[72], sSt[72], sSq[72];            // 864 B
    __shared__ float sSr[9], sSqr[9], sscal[3];             // 84 B
    __shared__ unsigned svcv[THREADS];                      // 2304 B

    const int tid = threadIdx.x;
    const int blk = blockIdx.x;
    const int b   = blk / (PPOS / POSB);
    const int rm  = blk % (PPOS / POSB);
    const int y   = rm / (SIDE / POSB);
    const int x0  = (rm % (SIDE / POSB)) * POSB;

    // ---- stage 1: neighbor vectors ----
    const int vec = tid >> 3, q = tid & 7;
    const int nb1 = vec >> 2, h1 = vec & 3;
    const int yy = y + nb1/6 - 1, xx = x0 + nb1%6 - 1;
    const bool vld = (yy >= 0) && (yy < SIDE) && (xx >= 0) && (xx < SIDE);
    const int npos = b*PPOS + yy*SIDE + xx;
    float4 v = make_float4(0.f, 0.f, 0.f, 0.f);
    if (vld) v = *reinterpret_cast<const float4*>(&hs[((size_t)npos*NHYP + h1)*FD + q*4]);

    // const rows -> sOutB rows 88-99
    {
        const unsigned* gsrc = reinterpret_cast<const unsigned*>(ws + WS_ROWS);
        for (int u = tid; u < 12*64; u += THREADS)
            sOutB[(88 + (u >> 6))*68 + (u & 63)] = gsrc[u];
    }
    if (tid < 9) { sSr[tid] = ws[WS_SR+tid]; sSqr[tid] = ws[WS_SQR+tid]; }
    if (tid < 3) sscal[tid] = ws[WS_SC+tid];

    {
        unsigned* drow = reinterpret_cast<unsigned*>(&snb[vec*40]);
        drow[q*2]   = packbf2(v.x, v.y);
        drow[q*2+1] = packbf2(v.z, v.w);
        float s  = v.x + v.y + v.z + v.w;
        float sq = v.x*v.x + v.y*v.y + v.z*v.z + v.w*v.w;
        s += __shfl_xor(s, 1); sq += __shfl_xor(sq, 1);
        s += __shfl_xor(s, 2); sq += __shfl_xor(sq, 2);
        s += __shfl_xor(s, 4); sq += __shfl_xor(sq, 4);
        if (q == 0) {
            sSt[vec] = s; sSq[vec] = sq;
            sact[vec] = vld ? act_in[npos*NHYP + h1] : 0.f;
        }
    }
    if (tid < 160) reinterpret_cast<unsigned*>(snb)[72*20 + tid] = 0u;  // zero pad rows 72-79
    __syncthreads();

    // ---- stage 2: MFMA GEMMs ----
    {
        const int wv = tid >> 6, lane = tid & 63;
        const int fr = lane & 15, fq = lane >> 4;
        const char* snbB = reinterpret_cast<const char*>(snb);
        if (wv < 8) {
            U8 bB, bA;
            bB.u4 = reinterpret_cast<const uint4*>(ws + WS_WBF)[wv*64 + lane];
            bA.u4 = reinterpret_cast<const uint4*>(ws + WS_WAF)[wv*64 + lane];
            #pragma unroll
            for (int m = 0; m < 5; ++m) {
                U8 a; a.u4 = *reinterpret_cast<const uint4*>(snbB + (m*16 + fr)*80 + fq*16);
                f32x4 acc = {0.f, 0.f, 0.f, 0.f};
                acc = __builtin_amdgcn_mfma_f32_16x16x32_bf16(a.s8, bB.s8, acc, 0, 0, 0);
                #pragma unroll
                for (int j = 0; j < 4; ++j) {
                    float o = __shfl_xor(acc[j], 1);
                    if (!(lane & 1))
                        sOutB[(m*16 + fq*4 + j)*68 + wv*8 + (fr >> 1)] = packbf2(acc[j], o);
                }
            }
            {   // G2: tgt rows 28-43 @ Wa -> rows 72-87
                U8 a; a.u4 = *reinterpret_cast<const uint4*>(snbB + (28 + fr)*80 + fq*16);
                f32x4 acc = {0.f, 0.f, 0.f, 0.f};
                acc = __builtin_amdgcn_mfma_f32_16x16x32_bf16(a.s8, bA.s8, acc, 0, 0, 0);
                #pragma unroll
                for (int j = 0; j < 4; ++j) {
                    float o = __shfl_xor(acc[j], 1);
                    if (!(lane & 1))
                        sOutB[(72 + fq*4 + j)*68 + wv*8 + (fr >> 1)] = packbf2(acc[j], o);
                }
            }
        } else {
            // G3: dot[c][s] = tgt @ src^T
            U8 t; t.u4 = *reinterpret_cast<const uint4*>(snbB + (28 + fr)*80 + fq*16);
            #pragma unroll
            for (int n = 0; n < 5; ++n) {
                U8 s2; s2.u4 = *reinterpret_cast<const uint4*>(snbB + (n*16 + fr)*80 + fq*16);
                f32x4 acc = {0.f, 0.f, 0.f, 0.f};
                acc = __builtin_amdgcn_mfma_f32_16x16x32_bf16(t.s8, s2.s8, acc, 0, 0, 0);
                *reinterpret_cast<f32x4*>(&sdot[(n*16 + fr)*20 + fq*4]) = acc;
            }
        }
    }
    __syncthreads();

    // ---- stage 3: per-row epilogue ----
    {
        const int pos = tid / 144, r = tid % 144;
        const int hh = r / 36, s = r % 36, k = s >> 2, h2 = s & 3;
        const int nbr  = (k/3)*6 + pos + (k%3);
        const int srow = nbr*4 + h2;
        const float gate = sact[srow];
        float svv = 0.f, cvv = 0.f;
        if (gate > 0.f) {
            const int cidx = pos*4 + hh;
            const int crow = 28 + cidx;
            const float dot = sdot[srow*20 + cidx];
            const float mu   = (2.f*sSt[crow] + sSr[k]) * (1.f/NJ);
            const float ssum = 2.f*sSq[crow] + 2.f*sSq[srow] - 2.f*dot + sSqr[k];
            const float rinv = rsqrtf(ssum*(1.f/NJ) - mu*mu + 1e-5f);
            const float beta = -mu*rinv;
            const uint4* pa = reinterpret_cast<const uint4*>(&sOutB[(72 + cidx)*68]);
            const uint4* pb = reinterpret_cast<const uint4*>(&sOutB[srow*68]);
            const uint4* pc = reinterpret_cast<const uint4*>(&sOutB[(88 + k)*68]);
            const uint4* pS = reinterpret_cast<const uint4*>(&sOutB[97*68]);
            const uint4* pT = reinterpret_cast<const uint4*>(&sOutB[98*68]);
            const uint4* pW = reinterpret_cast<const uint4*>(&sOutB[99*68]);
            float outs = 0.f, outc = 0.f;
            #pragma unroll 2
            for (int jq = 0; jq < 16; ++jq) {
                uint4 ua = pa[jq], ub = pb[jq], uc = pc[jq];
                uint4 uS = pS[jq], uT = pT[jq], uW = pW[jq];
                float accv = 0.f;
                #define ELEM(CA,CB,CC,CS,CT,CW,EXT) { \
                    float d  = EXT(CA) + EXT(CB) + EXT(CC); \
                    float pv = fmaf(rinv, d, fmaf(beta, EXT(CS), EXT(CT))); \
                    accv += fast_gelu(pv) * EXT(CW); }
                ELEM(ua.x, ub.x, uc.x, uS.x, uT.x, uW.x, bflo)
                ELEM(ua.x, ub.x, uc.x, uS.x, uT.x, uW.x, bfhi)
                ELEM(ua.y, ub.y, uc.y, uS.y, uT.y, uW.y, bflo)
                ELEM(ua.y, ub.y, uc.y, uS.y, uT.y, uW.y, bfhi)
                ELEM(ua.z, ub.z, uc.z, uS.z, uT.z, uW.z, bflo)
                ELEM(ua.z, ub.z, uc.z, uS.z, uT.z, uW.z, bfhi)
                ELEM(ua.w, ub.w, uc.w, uS.w, uT.w, uW.w, bflo)
                ELEM(ua.w, ub.w, uc.w, uS.w, uT.w, uW.w, bfhi)
                #undef ELEM
                if (jq < 8) outs += accv; else outc += accv;
            }
            svv = softplusf(outs + sscal[0]);
            cvv = softplusf(outc + sscal[1]);
        }
        svcv[tid] = packbf2(svv*gate, cvv*gate);
    }
    __syncthreads();

    // ---- stage 4: gated reduction + outputs + per-block scalar partials ----
    if (tid < 64) {
        const int pos4 = tid >> 4, hh4 = (tid >> 2) & 3, qq = tid & 3;
        float svs = 0.f, cvs = 0.f, mass = 0.f;
        #pragma unroll
        for (int i = 0; i < 9; ++i) {
            int s = qq*9 + i;
            unsigned pp = svcv[pos4*144 + hh4*36 + s];
            svs += bflo(pp); cvs += bfhi(pp);
            int kk = s >> 2, h2 = s & 3;
            int nbr = (kk/3)*6 + pos4 + (kk%3);
            mass += sact[nbr*4 + h2];
        }
        svs += __shfl_xor(svs, 1); cvs += __shfl_xor(cvs, 1); mass += __shfl_xor(mass, 1);
        svs += __shfl_xor(svs, 2); cvs += __shfl_xor(cvs, 2); mass += __shfl_xor(mass, 2);
        float bl = 0.f, en = 0.f, ar = 0.f;
        if (qq == 0) {
            mass = fmaxf(mass, 1e-6f);
            const float support  = svs / mass;
            const float conflict = cvs / mass;
            const int bph = (b*PPOS + y*SIDE + x0 + pos4)*NHYP + hh4;
            const float pd = drive[bph]  + support;
            const float pr = resist[bph] + conflict;
            float e = fminf(fmaxf(pd - pr + sscal[2], -3.f), 3.f);
            const float a = 1.f / (1.f + expf(-e));
            out[0*NOUT + bph] = support;
            out[1*NOUT + bph] = conflict;
            out[2*NOUT + bph] = pd;
            out[3*NOUT + bph] = pr;
            out[4*NOUT + bph] = e;
            out[5*NOUT + bph] = a;
            out[6*NOUT + bph] = mass;
            bl = a;
            en = -(a*logf(a + 1e-8f) + (1.f - a)*logf(1.f - a + 1e-8f));
            ar = (a > 0.5f) ? 1.f : 0.f;
        }
        #pragma unroll
        for (int off = 32; off > 0; off >>= 1) {
            bl += __shfl_down(bl, off); en += __shfl_down(en, off); ar += __shfl_down(ar, off);
        }
        if (tid == 0) {
            ws[WS_PART + blk]          = bl;
            ws[WS_PART + NBLK + blk]   = en;
            ws[WS_PART + 2*NBLK + blk] = ar;
        }
    }
}

// ---------------- final: reduce per-block partials ----------------
__global__ __launch_bounds__(256) void eml_final(const float* __restrict__ ws, float* __restrict__ out3)
{
    __shared__ float red[4*3];
    float bl = 0.f, en = 0.f, ar = 0.f;
    for (int i = threadIdx.x; i < NBLK; i += 256) {
        bl += ws[WS_PART + i];
        en += ws[WS_PART + NBLK + i];
        ar += ws[WS_PART + 2*NBLK + i];
    }
    #pragma unroll
    for (int off = 32; off > 0; off >>= 1) {
        bl += __shfl_down(bl, off); en += __shfl_down(en, off); ar += __shfl_down(ar, off);
    }
    const int lane = threadIdx.x & 63, wid = threadIdx.x >> 6;
    if (lane == 0) { red[wid*3] = bl; red[wid*3+1] = en; red[wid*3+2] = ar; }
    __syncthreads();
    if (threadIdx.x == 0) {
        float b2 = 0.f, e2 = 0.f, a2 = 0.f;
        for (int w = 0; w < 4; ++w) { b2 += red[w*3]; e2 += red[w*3+1]; a2 += red[w*3+2]; }
        const float inv = 1.0f / (float)NOUT;
        out3[0] = b2*inv; out3[1] = e2*inv; out3[2] = a2*inv;
    }
}

extern "C" void kernel_launch(void* const* d_in, const int* in_sizes, int n_in,
                              void* d_out, int out_size, void* d_ws, size_t ws_size,
                              hipStream_t stream)
{
    (void)in_sizes; (void)n_in; (void)out_size; (void)ws_size;
    const float* hs    = (const float*)d_in[0];
    const float* act   = (const float*)d_in[1];
    const float* drv   = (const float*)d_in[2];
    const float* res   = (const float*)d_in[3];
    const float* rel   = (const float*)d_in[4];
    const float* lnw   = (const float*)d_in[5];
    const float* lnb   = (const float*)d_in[6];
    const float* sw1   = (const float*)d_in[7];
    const float* sb1   = (const float*)d_in[8];
    const float* sw2   = (const float*)d_in[9];
    const float* sb2   = (const float*)d_in[10];
    const float* cw1   = (const float*)d_in[11];
    const float* cb1   = (const float*)d_in[12];
    const float* cw2   = (const float*)d_in[13];
    const float* cb2   = (const float*)d_in[14];
    const float* ebias = (const float*)d_in[15];
    float* out = (float*)d_out;
    float* ws  = (float*)d_ws;

    eml_fold<<<dim3(1), dim3(576), 0, stream>>>(
        rel, lnw, lnb, sw1, sb1, sw2, sb2, cw1, cb1, cw2, cb2, ebias, ws);
    eml_main<<<dim3(NBLK), dim3(THREADS), 0, stream>>>(hs, act, drv, res, out, ws);
    eml_final<<<dim3(1), dim3(256), 0, stream>>>(ws, out + 7*NOUT);
}

// Round 5
// 84.815 us; speedup vs baseline: 415.8389x; 1.2891x over previous
//
#include <hip/hip_runtime.h>
#include <hip/hip_bf16.h>
#include <math.h>

#define SIDE 48
#define PPOS (SIDE*SIDE)
#define NBATCH 2
#define NHYP 4
#define FD 32
#define RD 8
#define NJ 104
#define NBP (NBATCH*PPOS)       // 4608
#define NOUT (NBP*NHYP)         // 18432
#define POSB 4
#define THREADS 576
#define NBLK (NBP/POSB)         // 1152
// d_ws dword offsets
#define WS_SR   16              // 9 f32
#define WS_SQR  28              // 9 f32
#define WS_SC   40              // 3 f32
#define WS_RC   64              // 9*128 f32 (rel_k @ C)
#define WS_S    1216            // 128 f32
#define WS_T    1344            // 128 f32
#define WS_W2   1472            // 128 f32
#define WS_WBF  1600            // 2048 dw: Wb B-fragments
#define WS_WAF  3648            // 2048 dw: Wa B-fragments
#define WS_PART 5696            // 3*NBLK f32

typedef __attribute__((ext_vector_type(8))) short short8;
typedef __attribute__((ext_vector_type(4))) float f32x4;
union U8 { uint4 u4; short8 s8; };

__device__ __forceinline__ float bflo(unsigned u) { return __uint_as_float(u << 16); }
__device__ __forceinline__ float bfhi(unsigned u) { return __uint_as_float(u & 0xffff0000u); }
__device__ __forceinline__ unsigned packbf2(float a, float b) {
    unsigned ua = __float_as_uint(a), ub = __float_as_uint(b);
    unsigned ra = (ua + 0x7fffu + ((ua >> 16) & 1u)) >> 16;
    unsigned rb = (ub + 0x7fffu + ((ub >> 16) & 1u)) & 0xffff0000u;
    return ra | rb;
}
__device__ __forceinline__ float softplusf(float v) {
    return fmaxf(v, 0.f) + log1pf(expf(-fabsf(v)));
}
__device__ __forceinline__ float fast_gelu(float x) {
    float e = exp2f(-2.4554668f * x);
    return x * __builtin_amdgcn_rcpf(1.f + e);
}

#define W1X(kk, j) ((j) < 64 ? sup_w1[(kk)*64 + (j)] : con_w1[(kk)*64 + (j) - 64])

// ---------------- pre-kernel: fold weights once ----------------
__global__ __launch_bounds__(576) void eml_fold(
    const float* __restrict__ rel, const float* __restrict__ ln_w, const float* __restrict__ ln_b,
    const float* __restrict__ sup_w1, const float* __restrict__ sup_b1,
    const float* __restrict__ sup_w2, const float* __restrict__ sup_b2,
    const float* __restrict__ con_w1, const float* __restrict__ con_b1,
    const float* __restrict__ con_w2, const float* __restrict__ con_b2,
    const float* __restrict__ eml_bias, float* __restrict__ ws)
{
    const int tid = threadIdx.x;
    unsigned* wsd = reinterpret_cast<unsigned*>(ws);

    // B-fragment layouts for MFMA: lane l holds W^T[col][k] pairs, k0=(l>>4)*8+2j
    for (int u = tid; u < 2*2048; u += 576) {
        int sel = u >> 11, v2 = u & 2047;
        int n = v2 >> 8, l = (v2 >> 2) & 63, j = v2 & 3;
        int k0 = (l >> 4)*8 + 2*j, col = n*16 + (l & 15);
        float lo, hi;
        if (sel == 0) {   // Wb (src)
            lo = ln_w[32+k0]*W1X(32+k0,col)     - ln_w[64+k0]*W1X(64+k0,col);
            hi = ln_w[32+k0+1]*W1X(32+k0+1,col) - ln_w[64+k0+1]*W1X(64+k0+1,col);
        } else {          // Wa (tgt)
            lo = ln_w[k0]*W1X(k0,col)     + ln_w[64+k0]*W1X(64+k0,col);
            hi = ln_w[k0+1]*W1X(k0+1,col) + ln_w[64+k0+1]*W1X(64+k0+1,col);
        }
        wsd[(sel ? WS_WAF : WS_WBF) + v2] = packbf2(lo, hi);
    }
    // rc rows (f32): rel_k @ C
    for (int u = tid; u < 9*128; u += 576) {
        int k = u >> 7, j = u & 127;
        float a = 0.f;
        #pragma unroll
        for (int i = 0; i < 8; ++i) a += rel[k*8+i] * ln_w[96+i] * W1X(96+i, j);
        ws[WS_RC + u] = a;
    }
    if (tid < 128) {
        float S = 0.f, T = 0.f;
        for (int kk = 0; kk < NJ; ++kk) { float w = W1X(kk, tid); S += ln_w[kk]*w; T += ln_b[kk]*w; }
        ws[WS_S + tid]  = S;
        ws[WS_T + tid]  = T + (tid < 64 ? sup_b1[tid] : con_b1[tid-64]);
        ws[WS_W2 + tid] = (tid < 64 ? sup_w2[tid] : con_w2[tid-64]);
    }
    if (tid < 9) {
        float s = 0.f, sq = 0.f;
        #pragma unroll
        for (int i = 0; i < 8; ++i) { float v = rel[tid*8+i]; s += v; sq += v*v; }
        ws[WS_SR+tid] = s; ws[WS_SQR+tid] = sq;
    }
    if (tid == 0) { ws[WS_SC] = sup_b2[0]; ws[WS_SC+1] = con_b2[0]; ws[WS_SC+2] = eml_bias[0]; }
}

// ---------------- main kernel ----------------
__global__ __launch_bounds__(THREADS) void eml_main(
    const float* __restrict__ hs, const float* __restrict__ act_in,
    const float* __restrict__ drive, const float* __restrict__ resist,
    float* __restrict__ out, float* __restrict__ ws)
{
    __shared__ __align__(16) float    sA[16*132];   // 8448 B  tgt@Wa f32, stride 132
    __shared__ __align__(16) unsigned sB[80*68];    // 21760 B src@Wb bf16-pair, stride 68 dw
    __shared__ __align__(16) __hip_bfloat16 snb[80*40]; // 6400 B, stride 80 B
    __shared__ __align__(16) float sdot[80*20];     // 6400 B
    __shared__ float sact[72], sSt[72], sSq[72];    // 864 B
    __shared__ unsigned svcv[THREADS];              // 2304 B

    const int tid = threadIdx.x;
    const int blk = blockIdx.x;
    const int b   = blk / (PPOS / POSB);
    const int rm  = blk % (PPOS / POSB);
    const int y   = rm / (SIDE / POSB);
    const int x0  = (rm % (SIDE / POSB)) * POSB;

    // ---- stage 1: neighbor vectors + sums + gates ----
    const int vec = tid >> 3, q = tid & 7;
    const int nb1 = vec >> 2, h1 = vec & 3;
    const int yy = y + nb1/6 - 1, xx = x0 + nb1%6 - 1;
    const bool vld = (yy >= 0) && (yy < SIDE) && (xx >= 0) && (xx < SIDE);
    const int npos = b*PPOS + yy*SIDE + xx;
    float4 v = make_float4(0.f, 0.f, 0.f, 0.f);
    if (vld) v = *reinterpret_cast<const float4*>(&hs[((size_t)npos*NHYP + h1)*FD + q*4]);
    {
        unsigned* drow = reinterpret_cast<unsigned*>(&snb[vec*40]);
        drow[q*2]   = packbf2(v.x, v.y);
        drow[q*2+1] = packbf2(v.z, v.w);
        float s  = v.x + v.y + v.z + v.w;
        float sq = v.x*v.x + v.y*v.y + v.z*v.z + v.w*v.w;
        s += __shfl_xor(s, 1); sq += __shfl_xor(sq, 1);
        s += __shfl_xor(s, 2); sq += __shfl_xor(sq, 2);
        s += __shfl_xor(s, 4); sq += __shfl_xor(sq, 4);
        if (q == 0) {
            sSt[vec] = s; sSq[vec] = sq;
            sact[vec] = vld ? act_in[npos*NHYP + h1] : 0.f;
        }
    }
    if (tid < 160) reinterpret_cast<unsigned*>(snb)[72*20 + tid] = 0u;  // zero rows 72-79
    __syncthreads();

    // ---- stage 2: MFMA GEMMs ----
    {
        const int wv = tid >> 6, lane = tid & 63;
        const int fr = lane & 15, fq = lane >> 4;
        const char* snbB = reinterpret_cast<const char*>(snb);
        if (wv < 8) {
            U8 bB, bA;
            bB.u4 = reinterpret_cast<const uint4*>(ws + WS_WBF)[wv*64 + lane];
            bA.u4 = reinterpret_cast<const uint4*>(ws + WS_WAF)[wv*64 + lane];
            #pragma unroll
            for (int m = 0; m < 5; ++m) {
                U8 a; a.u4 = *reinterpret_cast<const uint4*>(snbB + (m*16 + fr)*80 + fq*16);
                f32x4 acc = {0.f, 0.f, 0.f, 0.f};
                acc = __builtin_amdgcn_mfma_f32_16x16x32_bf16(a.s8, bB.s8, acc, 0, 0, 0);
                #pragma unroll
                for (int j = 0; j < 4; ++j) {
                    float o = __shfl_xor(acc[j], 1);
                    if (!(lane & 1))
                        sB[(m*16 + fq*4 + j)*68 + wv*8 + (fr >> 1)] = packbf2(acc[j], o);
                }
            }
            {   // G2: tgt rows @ Wa -> sA (f32, direct)
                U8 a; a.u4 = *reinterpret_cast<const uint4*>(snbB + (28 + fr)*80 + fq*16);
                f32x4 acc = {0.f, 0.f, 0.f, 0.f};
                acc = __builtin_amdgcn_mfma_f32_16x16x32_bf16(a.s8, bA.s8, acc, 0, 0, 0);
                #pragma unroll
                for (int j = 0; j < 4; ++j)
                    sA[(fq*4 + j)*132 + wv*16 + fr] = acc[j];
            }
        } else {
            // G3: dot[src][c] = tgt @ src^T
            U8 t; t.u4 = *reinterpret_cast<const uint4*>(snbB + (28 + fr)*80 + fq*16);
            #pragma unroll
            for (int n = 0; n < 5; ++n) {
                U8 s2; s2.u4 = *reinterpret_cast<const uint4*>(snbB + (n*16 + fr)*80 + fq*16);
                f32x4 acc = {0.f, 0.f, 0.f, 0.f};
                acc = __builtin_amdgcn_mfma_f32_16x16x32_bf16(t.s8, s2.s8, acc, 0, 0, 0);
                *reinterpret_cast<f32x4*>(&sdot[(n*16 + fr)*20 + fq*4]) = acc;
            }
        }
    }
    __syncthreads();

    // ---- stage 3: per-row epilogue ----
    {
        const int pos = tid / 144, r = tid % 144;
        const int hh = r / 36, s = r % 36, k = s >> 2, h2 = s & 3;
        const int nbr  = (k/3)*6 + pos + (k%3);
        const int srow = nbr*4 + h2;
        const float gate = sact[srow];
        float svv = 0.f, cvv = 0.f;
        if (gate > 0.f) {
            const int cidx = pos*4 + hh;
            const int crow = 28 + cidx;
            const float dot = sdot[srow*20 + cidx];
            const float mu   = (2.f*sSt[crow] + ws[WS_SR+k]) * (1.f/NJ);
            const float ssum = 2.f*sSq[crow] + 2.f*sSq[srow] - 2.f*dot + ws[WS_SQR+k];
            const float rinv = rsqrtf(ssum*(1.f/NJ) - mu*mu + 1e-5f);
            const float beta = -mu*rinv;
            const float* rck = ws + WS_RC + k*128;
            const float* aR  = &sA[cidx*132];
            const uint4* bR  = reinterpret_cast<const uint4*>(&sB[srow*68]);
            float outs = 0.f, outc = 0.f;
            #pragma unroll 4
            for (int jq = 0; jq < 16; ++jq) {
                uint4  ub = bR[jq];
                float4 a0 = *reinterpret_cast<const float4*>(aR + jq*8);
                float4 a1 = *reinterpret_cast<const float4*>(aR + jq*8 + 4);
                float4 c0 = *reinterpret_cast<const float4*>(rck + jq*8);
                float4 c1 = *reinterpret_cast<const float4*>(rck + jq*8 + 4);
                float accv = 0.f;
                #define ELEM(AV,BV,CV,JI) { \
                    float d  = AV + BV + CV; \
                    float pv = fmaf(rinv, d, fmaf(beta, ws[WS_S + jq*8 + JI], ws[WS_T + jq*8 + JI])); \
                    accv += fast_gelu(pv) * ws[WS_W2 + jq*8 + JI]; }
                ELEM(a0.x, bflo(ub.x), c0.x, 0)
                ELEM(a0.y, bfhi(ub.x), c0.y, 1)
                ELEM(a0.z, bflo(ub.y), c0.z, 2)
                ELEM(a0.w, bfhi(ub.y), c0.w, 3)
                ELEM(a1.x, bflo(ub.z), c1.x, 4)
                ELEM(a1.y, bfhi(ub.z), c1.y, 5)
                ELEM(a1.z, bflo(ub.w), c1.z, 6)
                ELEM(a1.w, bfhi(ub.w), c1.w, 7)
                #undef ELEM
                if (jq < 8) outs += accv; else outc += accv;
            }
            svv = softplusf(outs + ws[WS_SC]);
            cvv = softplusf(outc + ws[WS_SC+1]);
        }
        svcv[tid] = packbf2(svv*gate, cvv*gate);
    }
    __syncthreads();

    // ---- stage 4: gated reduction + outputs + per-block scalar partials ----
    if (tid < 64) {
        const int pos4 = tid >> 4, hh4 = (tid >> 2) & 3, qq = tid & 3;
        float svs = 0.f, cvs = 0.f, mass = 0.f;
        #pragma unroll
        for (int i = 0; i < 9; ++i) {
            int s = qq*9 + i;
            unsigned pp = svcv[pos4*144 + hh4*36 + s];
            svs += bflo(pp); cvs += bfhi(pp);
            int kk = s >> 2, h2 = s & 3;
            int nbr = (kk/3)*6 + pos4 + (kk%3);
            mass += sact[nbr*4 + h2];
        }
        svs += __shfl_xor(svs, 1); cvs += __shfl_xor(cvs, 1); mass += __shfl_xor(mass, 1);
        svs += __shfl_xor(svs, 2); cvs += __shfl_xor(cvs, 2); mass += __shfl_xor(mass, 2);
        float bl = 0.f, en = 0.f, ar = 0.f;
        if (qq == 0) {
            mass = fmaxf(mass, 1e-6f);
            const float support  = svs / mass;
            const float conflict = cvs / mass;
            const int bph = (b*PPOS + y*SIDE + x0 + pos4)*NHYP + hh4;
            const float pd = drive[bph]  + support;
            const float pr = resist[bph] + conflict;
            float e = fminf(fmaxf(pd - pr + ws[WS_SC+2], -3.f), 3.f);
            const float a = 1.f / (1.f + expf(-e));
            out[0*NOUT + bph] = support;
            out[1*NOUT + bph] = conflict;
            out[2*NOUT + bph] = pd;
            out[3*NOUT + bph] = pr;
            out[4*NOUT + bph] = e;
            out[5*NOUT + bph] = a;
            out[6*NOUT + bph] = mass;
            bl = a;
            en = -(a*logf(a + 1e-8f) + (1.f - a)*logf(1.f - a + 1e-8f));
            ar = (a > 0.5f) ? 1.f : 0.f;
        }
        #pragma unroll
        for (int off = 32; off > 0; off >>= 1) {
            bl += __shfl_down(bl, off); en += __shfl_down(en, off); ar += __shfl_down(ar, off);
        }
        if (tid == 0) {
            ws[WS_PART + blk]          = bl;
            ws[WS_PART + NBLK + blk]   = en;
            ws[WS_PART + 2*NBLK + blk] = ar;
        }
    }
}

// ---------------- final: reduce per-block partials ----------------
__global__ __launch_bounds__(256) void eml_final(const float* __restrict__ ws, float* __restrict__ out3)
{
    __shared__ float red[4*3];
    float bl = 0.f, en = 0.f, ar = 0.f;
    for (int i = threadIdx.x; i < NBLK; i += 256) {
        bl += ws[WS_PART + i];
        en += ws[WS_PART + NBLK + i];
        ar += ws[WS_PART + 2*NBLK + i];
    }
    #pragma unroll
    for (int off = 32; off > 0; off >>= 1) {
        bl += __shfl_down(bl, off); en += __shfl_down(en, off); ar += __shfl_down(ar, off);
    }
    const int lane = threadIdx.x & 63, wid = threadIdx.x >> 6;
    if (lane == 0) { red[wid*3] = bl; red[wid*3+1] = en; red[wid*3+2] = ar; }
    __syncthreads();
    if (threadIdx.x == 0) {
        float b2 = 0.f, e2 = 0.f, a2 = 0.f;
        for (int w = 0; w < 4; ++w) { b2 += red[w*3]; e2 += red[w*3+1]; a2 += red[w*3+2]; }
        const float inv = 1.0f / (float)NOUT;
        out3[0] = b2*inv; out3[1] = e2*inv; out3[2] = a2*inv;
    }
}

extern "C" void kernel_launch(void* const* d_in, const int* in_sizes, int n_in,
                              void* d_out, int out_size, void* d_ws, size_t ws_size,
                              hipStream_t stream)
{
    (void)in_sizes; (void)n_in; (void)out_size; (void)ws_size;
    const float* hs    = (const float*)d_in[0];
    const float* act   = (const float*)d_in[1];
    const float* drv   = (const float*)d_in[2];
    const float* res   = (const float*)d_in[3];
    const float* rel   = (const float*)d_in[4];
    const float* lnw   = (const float*)d_in[5];
    const float* lnb   = (const float*)d_in[6];
    const float* sw1   = (const float*)d_in[7];
    const float* sb1   = (const float*)d_in[8];
    const float* sw2   = (const float*)d_in[9];
    const float* sb2   = (const float*)d_in[10];
    const float* cw1   = (const float*)d_in[11];
    const float* cb1   = (const float*)d_in[12];
    const float* cw2   = (const float*)d_in[13];
    const float* cb2   = (const float*)d_in[14];
    const float* ebias = (const float*)d_in[15];
    float* out = (float*)d_out;
    float* ws  = (float*)d_ws;

    eml_fold<<<dim3(1), dim3(576), 0, stream>>>(
        rel, lnw, lnb, sw1, sb1, sw2, sb2, cw1, cb1, cw2, cb2, ebias, ws);
    eml_main<<<dim3(NBLK), dim3(THREADS), 0, stream>>>(hs, act, drv, res, out, ws);
    eml_final<<<dim3(1), dim3(256), 0, stream>>>(ws, out + 7*NOUT);
}